// Round 1
// 1286.234 us; speedup vs baseline: 1.0217x; 1.0217x over previous
//
#include <hip/hip_runtime.h>

#define G_NUM 256
#define D_DIM 128

// ---------------- kernel 0: zero the workspace accumulators ----------------
__global__ void zero_ws_kernel(float* __restrict__ ws, int n) {
    int i = blockIdx.x * blockDim.x + threadIdx.x;
    if (i < n) ws[i] = 0.0f;
}

// ---------------- kernel 1: segmented sum + count (batch is sorted) --------
// v2: run-based, branch-free streaming.
// Per block: chunk of rows_per_block contiguous rows. Since batch is sorted,
// the chunk is a small number of segment runs (usually 1, sometimes 2).
// For each run: wave-uniform binary search finds the run end (≤10 cached
// scalar loads), then a 4x-unrolled, branch-free float4 accumulate loop with
// NO per-row batch reads streams the run at full HBM bandwidth (4 independent
// dwordx4 loads in flight per thread). One atomic flush per run.
// Layout: 256 threads = 8 row-groups (sub) x 32 lanes; lane owns one float4
// (16B) of the 512B row -> fully coalesced.
__global__ __launch_bounds__(256) void seg_sum_kernel(
    const float4* __restrict__ x4, const int* __restrict__ batch,
    float* __restrict__ sums, unsigned int* __restrict__ counts,
    int n_rows, int rows_per_block)
{
    const int lane = threadIdx.x & 31;   // float4 slot within the row
    const int sub  = threadIdx.x >> 5;   // which of 8 concurrent rows
    const int row_start = blockIdx.x * rows_per_block;
    const int row_end   = min(n_rows, row_start + rows_per_block);
    if (row_start >= row_end) return;

    const int b_last = batch[row_end - 1];

    int rs = row_start;
    while (rs < row_end) {
        const int b = batch[rs];           // wave-uniform
        int re;
        if (b == b_last) {
            re = row_end;                  // fast common case: run reaches chunk end
        } else {
            // first index in (rs, row_end-1] with batch != b (batch sorted)
            int lo = rs + 1, hi = row_end - 1;   // invariant: batch[hi] != b
            while (lo < hi) {
                const int mid = (lo + hi) >> 1;
                if (batch[mid] == b) lo = mid + 1; else hi = mid;
            }
            re = lo;
        }

        // ---- branch-free accumulate over rows [rs, re) of segment b ----
        float4 acc = make_float4(0.f, 0.f, 0.f, 0.f);
        int r = rs + sub;
        for (; r + 24 < re; r += 32) {     // 4 row-steps of 8, independent loads
            const float4 v0 = x4[(size_t)(r     ) * (D_DIM / 4) + lane];
            const float4 v1 = x4[(size_t)(r +  8) * (D_DIM / 4) + lane];
            const float4 v2 = x4[(size_t)(r + 16) * (D_DIM / 4) + lane];
            const float4 v3 = x4[(size_t)(r + 24) * (D_DIM / 4) + lane];
            acc.x += (v0.x + v1.x) + (v2.x + v3.x);
            acc.y += (v0.y + v1.y) + (v2.y + v3.y);
            acc.z += (v0.z + v1.z) + (v2.z + v3.z);
            acc.w += (v0.w + v1.w) + (v2.w + v3.w);
        }
        for (; r < re; r += 8) {           // remainder
            const float4 v = x4[(size_t)r * (D_DIM / 4) + lane];
            acc.x += v.x; acc.y += v.y; acc.z += v.z; acc.w += v.w;
        }

        // ---- one flush per run ----
        float* dst = sums + (size_t)b * D_DIM + lane * 4;
        atomicAdd(dst + 0, acc.x);
        atomicAdd(dst + 1, acc.y);
        atomicAdd(dst + 2, acc.z);
        atomicAdd(dst + 3, acc.w);
        if (threadIdx.x == 0) atomicAdd(&counts[b], (unsigned int)(re - rs));

        rs = re;
    }
}

// ---------------- kernel 2: mean + MLP head --------------------------------
// One wave (64 threads) per graph. mean row staged in LDS (broadcast reads,
// conflict-free); thread j computes h[j] = relu(mean . W1[:,j] + b1[j]) with
// coalesced W1 reads (W1 row-major [128,64]); then 64-lane shuffle reduction
// of h[j]*W2[j].
__global__ __launch_bounds__(64) void mlp_kernel(
    const float* __restrict__ sums, const unsigned int* __restrict__ counts,
    const float* __restrict__ W1, const float* __restrict__ b1,
    const float* __restrict__ W2, const float* __restrict__ b2,
    float* __restrict__ out)
{
    const int g = blockIdx.x;
    const int j = threadIdx.x;   // 0..63
    __shared__ float mean_s[D_DIM];

    const float c = (float)counts[g];
    mean_s[j]      = sums[(size_t)g * D_DIM + j]      / c;
    mean_s[j + 64] = sums[(size_t)g * D_DIM + j + 64] / c;
    __syncthreads();

    float acc = b1[j];
#pragma unroll 8
    for (int k = 0; k < D_DIM; ++k)
        acc += mean_s[k] * W1[k * (D_DIM / 2) + j];

    float p = fmaxf(acc, 0.0f) * W2[j];

    // 64-lane wave reduction
    for (int off = 32; off > 0; off >>= 1)
        p += __shfl_down(p, off, 64);

    if (j == 0) out[g] = p + b2[0];
}

// ---------------- launch ---------------------------------------------------
extern "C" void kernel_launch(void* const* d_in, const int* in_sizes, int n_in,
                              void* d_out, int out_size, void* d_ws, size_t ws_size,
                              hipStream_t stream) {
    const float* x     = (const float*)d_in[0];
    const int*   batch = (const int*)d_in[1];
    const float* W1    = (const float*)d_in[2];
    const float* b1    = (const float*)d_in[3];
    const float* W2    = (const float*)d_in[4];
    const float* b2    = (const float*)d_in[5];
    float*       out   = (float*)d_out;

    const int n_rows = in_sizes[1];   // N (batch index array length)

    float*        sums   = (float*)d_ws;
    unsigned int* counts = (unsigned int*)((char*)d_ws + (size_t)G_NUM * D_DIM * sizeof(float));

    // zero sums + counts (contiguous, both zero-bit-pattern)
    const int zero_n = G_NUM * D_DIM + G_NUM;
    zero_ws_kernel<<<(zero_n + 255) / 256, 256, 0, stream>>>((float*)d_ws, zero_n);

    const int nblocks = 2048;
    const int rows_per_block = (n_rows + nblocks - 1) / nblocks;
    seg_sum_kernel<<<nblocks, 256, 0, stream>>>(
        (const float4*)x, batch, sums, counts, n_rows, rows_per_block);

    mlp_kernel<<<G_NUM, 64, 0, stream>>>(sums, counts, W1, b1, W2, b2, out);
}